// Round 9
// baseline (140.143 us; speedup 1.0000x reference)
//
#include <hip/hip_runtime.h>
#include <math.h>

#define DD 64      // feature dim
#define MM 128     // time points per path
#define RS 133     // inc LDS row stride (words): banks (r*5+lane)%32 -> exact 2-way, free
#define OD 66      // odd-column plane offset within a row

typedef float  f32x4v __attribute__((ext_vector_type(4)));
typedef __bf16 bf16x8 __attribute__((ext_vector_type(8)));

#define FOR8(F) F(0) F(1) F(2) F(3) F(4) F(5) F(6) F(7)

union FragU { unsigned int u[4]; bf16x8 v; };

// RNE f32x2 -> packed bf16x2
__device__ __forceinline__ unsigned cvtpk(float lo, float hi) {
    unsigned r;
    asm("v_cvt_pk_bf16_f32 %0, %1, %2" : "=v"(r) : "v"(lo), "v"(hi));
    return r;
}

// bf16 frag of (row1 - row0), 8 consecutive floats, hi part only
__device__ __forceinline__ bf16x8 dfrag_hi(const float* __restrict__ r0,
                                           const float* __restrict__ r1) {
    float4 a0 = *(const float4*)r0, a1 = *(const float4*)(r0 + 4);
    float4 b0 = *(const float4*)r1, b1 = *(const float4*)(r1 + 4);
    FragU f;
    f.u[0] = cvtpk(b0.x - a0.x, b0.y - a0.y);
    f.u[1] = cvtpk(b0.z - a0.z, b0.w - a0.w);
    f.u[2] = cvtpk(b1.x - a1.x, b1.y - a1.y);
    f.u[3] = cvtpk(b1.z - a1.z, b1.w - a1.w);
    return f.v;
}

// bf16 hi + lo (residual) frags of (row1 - row0), loading from pointers
__device__ __forceinline__ void dfrag_hilo(const float* __restrict__ r0,
                                           const float* __restrict__ r1,
                                           bf16x8& hi, bf16x8& lo) {
    float4 a0 = *(const float4*)r0, a1 = *(const float4*)(r0 + 4);
    float4 b0 = *(const float4*)r1, b1 = *(const float4*)(r1 + 4);
    float d0 = b0.x - a0.x, d1 = b0.y - a0.y, d2 = b0.z - a0.z, d3 = b0.w - a0.w;
    float d4 = b1.x - a1.x, d5 = b1.y - a1.y, d6 = b1.z - a1.z, d7 = b1.w - a1.w;
    FragU H, L;
    H.u[0] = cvtpk(d0, d1); H.u[1] = cvtpk(d2, d3);
    H.u[2] = cvtpk(d4, d5); H.u[3] = cvtpk(d6, d7);
    float e0 = d0 - __uint_as_float(H.u[0] << 16);
    float e1 = d1 - __uint_as_float(H.u[0] & 0xffff0000u);
    float e2 = d2 - __uint_as_float(H.u[1] << 16);
    float e3 = d3 - __uint_as_float(H.u[1] & 0xffff0000u);
    float e4 = d4 - __uint_as_float(H.u[2] << 16);
    float e5 = d5 - __uint_as_float(H.u[2] & 0xffff0000u);
    float e6 = d6 - __uint_as_float(H.u[3] << 16);
    float e7 = d7 - __uint_as_float(H.u[3] & 0xffff0000u);
    L.u[0] = cvtpk(e0, e1); L.u[1] = cvtpk(e2, e3);
    L.u[2] = cvtpk(e4, e5); L.u[3] = cvtpk(e6, e7);
    hi = H.v; lo = L.v;
}

// ---- wave64 inclusive add-scan via DPP (proven rounds 2-8) ----
template<int CTRL, int RM, bool BC>
__device__ __forceinline__ float dpp_add(float x) {
    int t = __builtin_amdgcn_update_dpp(0, __float_as_int(x), CTRL, RM, 0xf, BC);
    return x + __int_as_float(t);
}
__device__ __forceinline__ float wave_incl_scan(float x) {
    x = dpp_add<0x111, 0xf, true >(x);   // row_shr:1
    x = dpp_add<0x112, 0xf, true >(x);   // row_shr:2
    x = dpp_add<0x114, 0xf, true >(x);   // row_shr:4
    x = dpp_add<0x118, 0xf, true >(x);   // row_shr:8
    x = dpp_add<0x142, 0xa, false>(x);   // row_bcast:15 -> rows 1,3
    x = dpp_add<0x143, 0xc, false>(x);   // row_bcast:31 -> rows 2,3
    return x;
}

// One wave per (gram, a, b) pair, compact grid (decode proven r2-r8).
// B-table: 16 named bf16x8 regs built once per pair (proven r5-r8).
//
// ROUND 9: occupancy experiment. r6-r8 showed OccupancyPercent tracks the
// __launch_bounds__ 2nd arg (compiler greedily allocates unified VGPR+AGPR
// up to the cap): (64,4)=128 cap spilled (r5), (64,2)=256 cap ran 2 waves/SIMD
// with both pipes <31% busy -- latency-bound on the serial DPP-scan chain.
// (64,3) caps at ~170 regs; dropping r8's A-prefetch (-32 live regs, was only
// worth 4 us) makes the ~140-reg live set fit => 3 waves/SIMD, +50% TLP.
__global__ __launch_bounds__(64, 3) void sig_goursat_kernel(
        const float* __restrict__ X, const float* __restrict__ Y,
        float* __restrict__ Kout)
{
    const int bid = blockIdx.x;
    int g, a, b;
    if (bid < 4160) {                  // symmetric grams, triangular index
        g = bid < 2080 ? 0 : 1;
        const int t = bid - g * 2080;
        float sq = sqrtf(4160.25f - 2.0f * (float)t);
        a = (int)(64.5f - sq);
        if (a < 0) a = 0; if (a > 63) a = 63;
        while (a > 0  && (a * (129 - a)) / 2 > t) --a;
        while (a < 63 && ((a + 1) * (128 - a)) / 2 <= t) ++a;
        b = a + (t - (a * (129 - a)) / 2);
    } else {
        const int t = bid - 4160;
        g = 2; a = t >> 6; b = t & 63;
    }

    const float* __restrict__ U = (g == 1 ? Y : X) + (size_t)a * (MM * DD);
    const float* __restrict__ V = (g == 0 ? X : Y) + (size_t)b * (MM * DD);

    const int lane = threadIdx.x;
    const int l15  = lane & 15;
    const int k8   = (lane >> 4) * 8;         // k-offset of this lane's frag
    const int rowg = (lane >> 4) * 4;         // C/D row group base

    __shared__ float incL[16 * RS];           // 2128 words = 8512 B

    // ---- B-frag register table: 16 named bf16x8 (64 regs), built once ----
#define TBDECL(ct) bf16x8 tb0_##ct, tb1_##ct;
    FOR8(TBDECL)
#define TBUILD(ct) { int brow_ = ct * 16 + l15; if (brow_ > 126) brow_ = 126; \
        const float* vp_ = V + (size_t)brow_ * DD + k8; \
        tb0_##ct = dfrag_hi(vp_,      vp_ + DD); \
        tb1_##ct = dfrag_hi(vp_ + 32, vp_ + DD + 32); }
    FOR8(TBUILD)

    float KL0 = 1.0f, KL1 = 1.0f;             // K[0][2l], K[0][2l+1] = 1
    const int wbase = rowg * RS + ((l15 & 1) ? OD : 0) + (l15 >> 1);

#define CTSTEP(ct) { f32x4v acc = {0.f, 0.f, 0.f, 0.f}; \
        acc = __builtin_amdgcn_mfma_f32_16x16x32_bf16(ahi0, tb0_##ct, acc, 0, 0, 0); \
        acc = __builtin_amdgcn_mfma_f32_16x16x32_bf16(alo0, tb0_##ct, acc, 0, 0, 0); \
        acc = __builtin_amdgcn_mfma_f32_16x16x32_bf16(ahi1, tb1_##ct, acc, 0, 0, 0); \
        acc = __builtin_amdgcn_mfma_f32_16x16x32_bf16(alo1, tb1_##ct, acc, 0, 0, 0); \
        const int w_ = wbase + ct * 8; \
        incL[w_]          = acc[0]; \
        incL[w_ + RS]     = acc[1]; \
        incL[w_ + 2*RS]   = acc[2]; \
        incL[w_ + 3*RS]   = acc[3]; }

#define SCANROW(r) { \
        const float iE = incL[(r) * RS + lane]; \
        const float iO = incL[(r) * RS + OD + lane]; \
        const float m0 = iE * KL0; \
        const float m1 = iO * KL1; \
        const float t_ = m0 + m1; \
        const float S_ = wave_incl_scan(t_); \
        const float ex = S_ - t_; \
        KL1 += ex + m0; \
        KL0 += ex; }

    for (int band = 0; band < 8; ++band) {
        // ---- A frags: rows p = band*16 + l15 (clamped), hi + lo residual ----
        int arow = band * 16 + l15; if (arow > 126) arow = 126;
        const float* ap = U + (size_t)arow * DD + k8;
        bf16x8 ahi0, alo0, ahi1, alo1;
        dfrag_hilo(ap,      ap + DD,      ahi0, alo0);
        dfrag_hilo(ap + 32, ap + DD + 32, ahi1, alo1);

        FOR8(CTSTEP)   // inc[16][128] for this band -> LDS

        // ---- fully-unrolled Goursat scan (p = band*16 + r; p=127 phantom) ----
        #pragma unroll
        for (int r = 0; r < 15; ++r) { SCANROW(r) }
        if (band < 7) { SCANROW(15) }
    }

    if (lane == 63) Kout[(size_t)g * 4096 + a * 64 + b] = KL1;   // K[127][127]
}

// Deterministic weighted reduction + the mean((X0-Y0)^2) term.
__global__ void sig_reduce_kernel(const float* __restrict__ X,
                                  const float* __restrict__ Y,
                                  const float* __restrict__ Kws,
                                  float* __restrict__ out)
{
    const int t = threadIdx.x;
    double accK = 0.0, acc2 = 0.0;
    for (int i = t; i < 4096; i += 256) {
        const int a = i >> 6, b = i & 63;
        if (a <= b) {
            const double w = (a == b) ? 1.0 : 2.0;
            accK += w * (double)Kws[i];           // XX
            accK += w * (double)Kws[4096 + i];    // YY
        }
        accK -= 2.0 * (double)Kws[8192 + i];      // XY
        const float df = X[(size_t)a * (MM * DD) + b] - Y[(size_t)a * (MM * DD) + b];
        acc2 += (double)df * (double)df;
    }
    __shared__ double red[256];
    red[t] = accK / 4096.0 + acc2 / 4096.0;
    __syncthreads();
    for (int s = 128; s > 0; s >>= 1) {
        if (t < s) red[t] += red[t + s];
        __syncthreads();
    }
    if (t == 0) out[0] = (float)red[0];
}

extern "C" void kernel_launch(void* const* d_in, const int* in_sizes, int n_in,
                              void* d_out, int out_size, void* d_ws, size_t ws_size,
                              hipStream_t stream) {
    const float* X = (const float*)d_in[0];
    const float* Y = (const float*)d_in[1];
    float* Kws = (float*)d_ws;          // 3 * 4096 floats
    float* out = (float*)d_out;

    sig_goursat_kernel<<<dim3(8256), dim3(64), 0, stream>>>(X, Y, Kws);
    sig_reduce_kernel<<<dim3(1), dim3(256), 0, stream>>>(X, Y, Kws, out);
}

// Round 10
// 125.403 us; speedup vs baseline: 1.1175x; 1.1175x over previous
//
#include <hip/hip_runtime.h>
#include <math.h>

#define DD 64      // feature dim
#define MM 128     // time points per path
#define RS 133     // inc LDS row stride (words)
#define OD 66      // odd-column plane offset within a row
#define P1 2128    // pair-1 plane offset (16*RS words)

typedef float  f32x4v __attribute__((ext_vector_type(4)));
typedef __bf16 bf16x8 __attribute__((ext_vector_type(8)));

#define FOR8(F) F(0) F(1) F(2) F(3) F(4) F(5) F(6) F(7)

union FragU { unsigned int u[4]; bf16x8 v; };

// RNE f32x2 -> packed bf16x2
__device__ __forceinline__ unsigned cvtpk(float lo, float hi) {
    unsigned r;
    asm("v_cvt_pk_bf16_f32 %0, %1, %2" : "=v"(r) : "v"(lo), "v"(hi));
    return r;
}

// bf16 frag of (row1 - row0), 8 consecutive floats (hi bits, RNE)
__device__ __forceinline__ bf16x8 dfrag_hi(const float* __restrict__ r0,
                                           const float* __restrict__ r1) {
    float4 a0 = *(const float4*)r0, a1 = *(const float4*)(r0 + 4);
    float4 b0 = *(const float4*)r1, b1 = *(const float4*)(r1 + 4);
    FragU f;
    f.u[0] = cvtpk(b0.x - a0.x, b0.y - a0.y);
    f.u[1] = cvtpk(b0.z - a0.z, b0.w - a0.w);
    f.u[2] = cvtpk(b1.x - a1.x, b1.y - a1.y);
    f.u[3] = cvtpk(b1.z - a1.z, b1.w - a1.w);
    return f.v;
}

// ---- wave64 inclusive add-scan via DPP (proven rounds 2-9) ----
template<int CTRL, int RM, bool BC>
__device__ __forceinline__ float dpp_add(float x) {
    int t = __builtin_amdgcn_update_dpp(0, __float_as_int(x), CTRL, RM, 0xf, BC);
    return x + __int_as_float(t);
}
__device__ __forceinline__ float wave_incl_scan(float x) {
    x = dpp_add<0x111, 0xf, true >(x);   // row_shr:1
    x = dpp_add<0x112, 0xf, true >(x);   // row_shr:2
    x = dpp_add<0x114, 0xf, true >(x);   // row_shr:4
    x = dpp_add<0x118, 0xf, true >(x);   // row_shr:8
    x = dpp_add<0x142, 0xa, false>(x);   // row_bcast:15 -> rows 1,3
    x = dpp_add<0x143, 0xc, false>(x);   // row_bcast:31 -> rows 2,3
    return x;
}

// ROUND 10: TWO pairs per wave, sharing the V column (shared 64-reg B-table;
// two fully independent Goursat scan chains interleave -> 2x ILP against the
// serial DPP/LDS/MFMA latency that r6-r9 showed dominates; dur was flat at
// ~140us across occupancy 20-44%). A-side lo-residual dropped (B-side has
// been bf16-hi-only since r4 with output error 0.0 -> safe): 2 MFMA per
// ct per stream.
//   grid: gram0 tri [0,1056) | gram1 tri [1056,2112) | gram2 full [2112,4160)
//   tri column b has ceil((b+1)/2) waves; off(b) = floor((b+1)^2/4);
//   wave j of column b covers a0=2j, a1=2j+1 (a1>b -> duplicate, masked store)
__global__ __launch_bounds__(64, 2) void sig_goursat_kernel(
        const float* __restrict__ X, const float* __restrict__ Y,
        float* __restrict__ Kout)
{
    const int bid = blockIdx.x;
    int g, a0, a1, bcol;
    bool dup = false;
    if (bid < 2112) {                  // symmetric grams, column-paired tri
        g = bid < 1056 ? 0 : 1;
        const int t = bid - g * 1056;
        bcol = (int)(2.0f * sqrtf((float)t + 1.0f));
        if (bcol > 63) bcol = 63;
        while (bcol > 0  && ((bcol + 1) * (bcol + 1)) / 4 > t) --bcol;
        while (bcol < 63 && ((bcol + 2) * (bcol + 2)) / 4 <= t) ++bcol;
        const int j = t - ((bcol + 1) * (bcol + 1)) / 4;
        a0 = 2 * j; a1 = 2 * j + 1;
        if (a1 > bcol) { a1 = a0; dup = true; }
    } else {
        const int t = bid - 2112;
        g = 2; bcol = t & 63;
        a0 = (t >> 6) * 2; a1 = a0 + 1;
    }

    const float* __restrict__ Ub = (g == 1 ? Y : X);
    const float* __restrict__ U0 = Ub + (size_t)a0 * (MM * DD);
    const float* __restrict__ U1 = Ub + (size_t)a1 * (MM * DD);
    const float* __restrict__ V  = (g == 0 ? X : Y) + (size_t)bcol * (MM * DD);

    const int lane = threadIdx.x;
    const int l15  = lane & 15;
    const int k8   = (lane >> 4) * 8;         // k-offset of this lane's frag
    const int rowg = (lane >> 4) * 4;         // C/D row group base

    __shared__ float incL[2 * P1];            // two planes of [16][RS]

    // ---- shared B-frag register table: 16 named bf16x8 (64 regs) ----
#define TBDECL(ct) bf16x8 tb0_##ct, tb1_##ct;
    FOR8(TBDECL)
#define TBUILD(ct) { int brow_ = ct * 16 + l15; if (brow_ > 126) brow_ = 126; \
        const float* vp_ = V + (size_t)brow_ * DD + k8; \
        tb0_##ct = dfrag_hi(vp_,      vp_ + DD); \
        tb1_##ct = dfrag_hi(vp_ + 32, vp_ + DD + 32); }
    FOR8(TBUILD)

    float s0e = 1.0f, s0o = 1.0f;             // stream 0: K[0][2l], K[0][2l+1]
    float s1e = 1.0f, s1o = 1.0f;             // stream 1
    const int wbase = rowg * RS + ((l15 & 1) ? OD : 0) + (l15 >> 1);

#define CTSTEP2(ct) { \
        f32x4v c0 = {0.f, 0.f, 0.f, 0.f}, c1 = {0.f, 0.f, 0.f, 0.f}; \
        c0 = __builtin_amdgcn_mfma_f32_16x16x32_bf16(a0k0, tb0_##ct, c0, 0, 0, 0); \
        c1 = __builtin_amdgcn_mfma_f32_16x16x32_bf16(a1k0, tb0_##ct, c1, 0, 0, 0); \
        c0 = __builtin_amdgcn_mfma_f32_16x16x32_bf16(a0k1, tb1_##ct, c0, 0, 0, 0); \
        c1 = __builtin_amdgcn_mfma_f32_16x16x32_bf16(a1k1, tb1_##ct, c1, 0, 0, 0); \
        const int w_ = wbase + ct * 8; \
        incL[w_]             = c0[0]; \
        incL[w_ + RS]        = c0[1]; \
        incL[w_ + 2*RS]      = c0[2]; \
        incL[w_ + 3*RS]      = c0[3]; \
        incL[P1 + w_]        = c1[0]; \
        incL[P1 + w_ + RS]   = c1[1]; \
        incL[P1 + w_ + 2*RS] = c1[2]; \
        incL[P1 + w_ + 3*RS] = c1[3]; }

#define SCANROW2(r) { \
        const float iE0 = incL[(r) * RS + lane]; \
        const float iO0 = incL[(r) * RS + OD + lane]; \
        const float iE1 = incL[P1 + (r) * RS + lane]; \
        const float iO1 = incL[P1 + (r) * RS + OD + lane]; \
        const float m0a = iE0 * s0e; \
        const float m1a = iO0 * s0o; \
        const float m0b = iE1 * s1e; \
        const float m1b = iO1 * s1o; \
        const float ta  = m0a + m1a; \
        const float tb  = m0b + m1b; \
        const float Sa  = wave_incl_scan(ta); \
        const float Sb  = wave_incl_scan(tb); \
        const float exa = Sa - ta; \
        const float exb = Sb - tb; \
        s0o += exa + m0a;  s0e += exa; \
        s1o += exb + m0b;  s1e += exb; }

    for (int band = 0; band < 8; ++band) {
        // ---- A frags, both streams, hi-only: rows p = band*16 + l15 ----
        int arow = band * 16 + l15; if (arow > 126) arow = 126;
        const float* ap0 = U0 + (size_t)arow * DD + k8;
        const float* ap1 = U1 + (size_t)arow * DD + k8;
        bf16x8 a0k0 = dfrag_hi(ap0,      ap0 + DD);
        bf16x8 a0k1 = dfrag_hi(ap0 + 32, ap0 + DD + 32);
        bf16x8 a1k0 = dfrag_hi(ap1,      ap1 + DD);
        bf16x8 a1k1 = dfrag_hi(ap1 + 32, ap1 + DD + 32);

        FOR8(CTSTEP2)   // inc[16][128] for both pairs -> LDS planes

        // ---- interleaved dual Goursat scan (p = band*16 + r; 127 phantom) ----
        #pragma unroll
        for (int r = 0; r < 15; ++r) { SCANROW2(r) }
        if (band < 7) { SCANROW2(15) }
    }

    if (lane == 63) {
        float* kg = Kout + (size_t)g * 4096;
        kg[a0 * 64 + bcol] = s0o;                 // K[127][127], stream 0
        if (!dup) kg[a1 * 64 + bcol] = s1o;       // stream 1
    }
}

// Deterministic weighted reduction + the mean((X0-Y0)^2) term.
__global__ void sig_reduce_kernel(const float* __restrict__ X,
                                  const float* __restrict__ Y,
                                  const float* __restrict__ Kws,
                                  float* __restrict__ out)
{
    const int t = threadIdx.x;
    double accK = 0.0, acc2 = 0.0;
    for (int i = t; i < 4096; i += 256) {
        const int a = i >> 6, b = i & 63;
        if (a <= b) {
            const double w = (a == b) ? 1.0 : 2.0;
            accK += w * (double)Kws[i];           // XX
            accK += w * (double)Kws[4096 + i];    // YY
        }
        accK -= 2.0 * (double)Kws[8192 + i];      // XY
        const float df = X[(size_t)a * (MM * DD) + b] - Y[(size_t)a * (MM * DD) + b];
        acc2 += (double)df * (double)df;
    }
    __shared__ double red[256];
    red[t] = accK / 4096.0 + acc2 / 4096.0;
    __syncthreads();
    for (int s = 128; s > 0; s >>= 1) {
        if (t < s) red[t] += red[t + s];
        __syncthreads();
    }
    if (t == 0) out[0] = (float)red[0];
}

extern "C" void kernel_launch(void* const* d_in, const int* in_sizes, int n_in,
                              void* d_out, int out_size, void* d_ws, size_t ws_size,
                              hipStream_t stream) {
    const float* X = (const float*)d_in[0];
    const float* Y = (const float*)d_in[1];
    float* Kws = (float*)d_ws;          // 3 * 4096 floats
    float* out = (float*)d_out;

    sig_goursat_kernel<<<dim3(4160), dim3(64), 0, stream>>>(X, Y, Kws);
    sig_reduce_kernel<<<dim3(1), dim3(256), 0, stream>>>(X, Y, Kws, out);
}

// Round 11
// 114.197 us; speedup vs baseline: 1.2272x; 1.0981x over previous
//
#include <hip/hip_runtime.h>
#include <math.h>

#define DD 64      // feature dim
#define MM 128     // time points per path
#define RSW 132    // inc LDS row stride in words (even: b64-aligned pairs; 2-way banks)
#define P1W 2112   // plane-1 offset in words (16*RSW)
#define RS2 66     // row stride in float2 units

typedef float  f32x4v __attribute__((ext_vector_type(4)));
typedef __bf16 bf16x8 __attribute__((ext_vector_type(8)));

#define FOR8(F) F(0) F(1) F(2) F(3) F(4) F(5) F(6) F(7)

union FragU { unsigned int u[4]; bf16x8 v; };

// RNE f32x2 -> packed bf16x2
__device__ __forceinline__ unsigned cvtpk(float lo, float hi) {
    unsigned r;
    asm("v_cvt_pk_bf16_f32 %0, %1, %2" : "=v"(r) : "v"(lo), "v"(hi));
    return r;
}

// bf16 frag of (row1 - row0), 8 consecutive floats (hi bits, RNE)
__device__ __forceinline__ bf16x8 dfrag_hi(const float* __restrict__ r0,
                                           const float* __restrict__ r1) {
    float4 a0 = *(const float4*)r0, a1 = *(const float4*)(r0 + 4);
    float4 b0 = *(const float4*)r1, b1 = *(const float4*)(r1 + 4);
    FragU f;
    f.u[0] = cvtpk(b0.x - a0.x, b0.y - a0.y);
    f.u[1] = cvtpk(b0.z - a0.z, b0.w - a0.w);
    f.u[2] = cvtpk(b1.x - a1.x, b1.y - a1.y);
    f.u[3] = cvtpk(b1.z - a1.z, b1.w - a1.w);
    return f.v;
}

// ---- wave64 inclusive add-scan via DPP (proven rounds 2-10) ----
template<int CTRL, int RM, bool BC>
__device__ __forceinline__ float dpp_add(float x) {
    int t = __builtin_amdgcn_update_dpp(0, __float_as_int(x), CTRL, RM, 0xf, BC);
    return x + __int_as_float(t);
}
__device__ __forceinline__ float wave_incl_scan(float x) {
    x = dpp_add<0x111, 0xf, true >(x);   // row_shr:1
    x = dpp_add<0x112, 0xf, true >(x);   // row_shr:2
    x = dpp_add<0x114, 0xf, true >(x);   // row_shr:4
    x = dpp_add<0x118, 0xf, true >(x);   // row_shr:8
    x = dpp_add<0x142, 0xa, false>(x);   // row_bcast:15 -> rows 1,3
    x = dpp_add<0x143, 0xc, false>(x);   // row_bcast:31 -> rows 2,3
    return x;
}

// ROUND 11: attack the LDS unit (r10 post-mortem: ~1530 scalar ds ops/wave +
// per-row exposed LDS latency explain the 100K-cyc wave wall while no pipe
// exceeds 30%).
//  - row-major inc[16][RSW=132]: lane's (iE,iO) = cols (2l,2l+1) are adjacent
//    -> ONE ds_read_b64 per plane per row (read ops halved; banks at floor).
//  - depth-2 row prefetch in the scan: row r math overlaps rows r+1/r+2 reads.
//  - (64,3): live set ~145 fits the ~170-reg cap; LDS (16.9KB) caps 9 blk/CU.
// Structure otherwise = r10: two pairs/wave sharing the V column's B-table,
// A-side bf16-hi-only (B-side hi-only since r4, output error 0.0).
__global__ __launch_bounds__(64, 3) void sig_goursat_kernel(
        const float* __restrict__ X, const float* __restrict__ Y,
        float* __restrict__ Kout)
{
    const int bid = blockIdx.x;
    int g, a0, a1, bcol;
    bool dup = false;
    if (bid < 2112) {                  // symmetric grams, column-paired tri
        g = bid < 1056 ? 0 : 1;
        const int t = bid - g * 1056;
        bcol = (int)(2.0f * sqrtf((float)t + 1.0f));
        if (bcol > 63) bcol = 63;
        while (bcol > 0  && ((bcol + 1) * (bcol + 1)) / 4 > t) --bcol;
        while (bcol < 63 && ((bcol + 2) * (bcol + 2)) / 4 <= t) ++bcol;
        const int j = t - ((bcol + 1) * (bcol + 1)) / 4;
        a0 = 2 * j; a1 = 2 * j + 1;
        if (a1 > bcol) { a1 = a0; dup = true; }
    } else {
        const int t = bid - 2112;
        g = 2; bcol = t & 63;
        a0 = (t >> 6) * 2; a1 = a0 + 1;
    }

    const float* __restrict__ Ub = (g == 1 ? Y : X);
    const float* __restrict__ U0 = Ub + (size_t)a0 * (MM * DD);
    const float* __restrict__ U1 = Ub + (size_t)a1 * (MM * DD);
    const float* __restrict__ V  = (g == 0 ? X : Y) + (size_t)bcol * (MM * DD);

    const int lane = threadIdx.x;
    const int l15  = lane & 15;
    const int k8   = (lane >> 4) * 8;         // k-offset of this lane's frag
    const int rowg = (lane >> 4) * 4;         // C/D row group base

    __shared__ float incL[2 * P1W];           // two planes of [16][RSW]

    // ---- shared B-frag register table: 16 named bf16x8 (64 regs) ----
#define TBDECL(ct) bf16x8 tb0_##ct, tb1_##ct;
    FOR8(TBDECL)
#define TBUILD(ct) { int brow_ = ct * 16 + l15; if (brow_ > 126) brow_ = 126; \
        const float* vp_ = V + (size_t)brow_ * DD + k8; \
        tb0_##ct = dfrag_hi(vp_,      vp_ + DD); \
        tb1_##ct = dfrag_hi(vp_ + 32, vp_ + DD + 32); }
    FOR8(TBUILD)

    float s0e = 1.0f, s0o = 1.0f;             // stream 0: K[0][2l], K[0][2l+1]
    float s1e = 1.0f, s1o = 1.0f;             // stream 1
    // writer base: row-major word = row*RSW + col; col = ct*16 + l15
    const int wbase = rowg * RSW + l15;

#define CTSTEP2(ct) { \
        f32x4v c0 = {0.f, 0.f, 0.f, 0.f}, c1 = {0.f, 0.f, 0.f, 0.f}; \
        c0 = __builtin_amdgcn_mfma_f32_16x16x32_bf16(a0k0, tb0_##ct, c0, 0, 0, 0); \
        c1 = __builtin_amdgcn_mfma_f32_16x16x32_bf16(a1k0, tb0_##ct, c1, 0, 0, 0); \
        c0 = __builtin_amdgcn_mfma_f32_16x16x32_bf16(a0k1, tb1_##ct, c0, 0, 0, 0); \
        c1 = __builtin_amdgcn_mfma_f32_16x16x32_bf16(a1k1, tb1_##ct, c1, 0, 0, 0); \
        const int w_ = wbase + ct * 16; \
        incL[w_]              = c0[0]; \
        incL[w_ + RSW]        = c0[1]; \
        incL[w_ + 2*RSW]      = c0[2]; \
        incL[w_ + 3*RSW]      = c0[3]; \
        incL[P1W + w_]        = c1[0]; \
        incL[P1W + w_ + RSW]  = c1[1]; \
        incL[P1W + w_ + 2*RSW]= c1[2]; \
        incL[P1W + w_ + 3*RSW]= c1[3]; }

    // scan row compute: e0/e1 hold (iE,iO) for stream 0/1
#define SCANROW2C(e0, e1) { \
        const float m0a = e0.x * s0e; \
        const float m1a = e0.y * s0o; \
        const float m0b = e1.x * s1e; \
        const float m1b = e1.y * s1o; \
        const float ta  = m0a + m1a; \
        const float tb  = m0b + m1b; \
        const float Sa  = wave_incl_scan(ta); \
        const float Sb  = wave_incl_scan(tb); \
        const float exa = Sa - ta; \
        const float exb = Sb - tb; \
        s0o += exa + m0a;  s0e += exa; \
        s1o += exb + m0b;  s1e += exb; }

    const float2* pl0 = (const float2*)&incL[2 * lane];        // plane 0
    const float2* pl1 = (const float2*)&incL[P1W + 2 * lane];  // plane 1

    for (int band = 0; band < 8; ++band) {
        // ---- A frags, both streams, hi-only: rows p = band*16 + l15 ----
        int arow = band * 16 + l15; if (arow > 126) arow = 126;
        const float* ap0 = U0 + (size_t)arow * DD + k8;
        const float* ap1 = U1 + (size_t)arow * DD + k8;
        bf16x8 a0k0 = dfrag_hi(ap0,      ap0 + DD);
        bf16x8 a0k1 = dfrag_hi(ap0 + 32, ap0 + DD + 32);
        bf16x8 a1k0 = dfrag_hi(ap1,      ap1 + DD);
        bf16x8 a1k1 = dfrag_hi(ap1 + 32, ap1 + DD + 32);

        FOR8(CTSTEP2)   // inc[16][128] for both pairs -> LDS planes

        // ---- dual Goursat scan, depth-2 LDS prefetch (rows in-order per wave)
        float2 e0 = pl0[0],   e1 = pl1[0];      // row 0
        float2 f0 = pl0[RS2], f1 = pl1[RS2];    // row 1
        #pragma unroll
        for (int r = 0; r < 14; ++r) {
            float2 n0 = pl0[(r + 2) * RS2];     // row r+2 issued before row r math
            float2 n1 = pl1[(r + 2) * RS2];
            SCANROW2C(e0, e1)
            e0 = f0; e1 = f1; f0 = n0; f1 = n1;
        }
        SCANROW2C(e0, e1)                       // row 14
        if (band < 7) { SCANROW2C(f0, f1) }     // row 15 (p=127 phantom on band 7)
    }

    if (lane == 63) {
        float* kg = Kout + (size_t)g * 4096;
        kg[a0 * 64 + bcol] = s0o;                 // K[127][127], stream 0
        if (!dup) kg[a1 * 64 + bcol] = s1o;       // stream 1
    }
}

// Deterministic weighted reduction + the mean((X0-Y0)^2) term.
__global__ void sig_reduce_kernel(const float* __restrict__ X,
                                  const float* __restrict__ Y,
                                  const float* __restrict__ Kws,
                                  float* __restrict__ out)
{
    const int t = threadIdx.x;
    double accK = 0.0, acc2 = 0.0;
    for (int i = t; i < 4096; i += 256) {
        const int a = i >> 6, b = i & 63;
        if (a <= b) {
            const double w = (a == b) ? 1.0 : 2.0;
            accK += w * (double)Kws[i];           // XX
            accK += w * (double)Kws[4096 + i];    // YY
        }
        accK -= 2.0 * (double)Kws[8192 + i];      // XY
        const float df = X[(size_t)a * (MM * DD) + b] - Y[(size_t)a * (MM * DD) + b];
        acc2 += (double)df * (double)df;
    }
    __shared__ double red[256];
    red[t] = accK / 4096.0 + acc2 / 4096.0;
    __syncthreads();
    for (int s = 128; s > 0; s >>= 1) {
        if (t < s) red[t] += red[t + s];
        __syncthreads();
    }
    if (t == 0) out[0] = (float)red[0];
}

extern "C" void kernel_launch(void* const* d_in, const int* in_sizes, int n_in,
                              void* d_out, int out_size, void* d_ws, size_t ws_size,
                              hipStream_t stream) {
    const float* X = (const float*)d_in[0];
    const float* Y = (const float*)d_in[1];
    float* Kws = (float*)d_ws;          // 3 * 4096 floats
    float* out = (float*)d_out;

    sig_goursat_kernel<<<dim3(4160), dim3(64), 0, stream>>>(X, Y, Kws);
    sig_reduce_kernel<<<dim3(1), dim3(256), 0, stream>>>(X, Y, Kws, out);
}